// Round 5
// baseline (230.892 us; speedup 1.0000x reference)
//
#include <hip/hip_runtime.h>

#define D 128
#define GROWS 64
#define CHUNK 4096

typedef __attribute__((ext_vector_type(8))) short short8;
typedef __attribute__((ext_vector_type(4))) float float4v;

// round-to-nearest-even fp32 -> bf16
__device__ __forceinline__ ushort f2bf(float x) {
    uint u = __float_as_uint(x);
    return (ushort)((u + 0x7FFFu + ((u >> 16) & 1u)) >> 16);
}

// ---------------------------------------------------------------------------
// Kernel 0: one-time W convert+transpose: Wtg[n*128+k] = bf16(W[k*128+n]).
// ---------------------------------------------------------------------------
__global__ __launch_bounds__(256) void convW_kernel(
    const float* __restrict__ W, ushort* __restrict__ Wtg)
{
    int idx = blockIdx.x * 256 + threadIdx.x;  // 16384 total
    int k = idx >> 7, n = idx & 127;
    Wtg[n * 128 + k] = f2bf(W[idx]);
}

// ---------------------------------------------------------------------------
// Kernel 1: z = h @ W via bf16 MFMA (16x16x32). B-fragments from global Wtg
// (32 KB, L1-hot). LDS h-tile (17 KB, stride 136) reused to stage bf16 z for
// coalesced uint4 writeback. Fused s_src/s_dst epilogue. NO atomic tail.
// ---------------------------------------------------------------------------
__global__ __launch_bounds__(256) void gemm_mfma_kernel(
    const float* __restrict__ h, const ushort* __restrict__ Wtg,
    const float* __restrict__ attn,
    ushort* __restrict__ zb, float* __restrict__ s_src, float* __restrict__ s_dst,
    int N)
{
    __shared__ ushort ht[GROWS * 136];  // h-tile, then z-tile
    const int tid = threadIdx.x;
    const int base = blockIdx.x * GROWS;

#pragma unroll
    for (int it = 0; it < 8; ++it) {
        int idx = it * 256 + tid;
        int r = idx >> 5, c4 = (idx & 31) * 4;
        float4 v = make_float4(0.f, 0.f, 0.f, 0.f);
        if (base + r < N) v = *(const float4*)&h[(size_t)(base + r) * D + c4];
        ushort4 u = make_ushort4(f2bf(v.x), f2bf(v.y), f2bf(v.z), f2bf(v.w));
        *(ushort4*)&ht[r * 136 + c4] = u;
    }
    __syncthreads();

    const int lane = tid & 63;
    const int wave = tid >> 6;
    const int col = lane & 15;
    const int quad = lane >> 4;
    const int wm = wave * 16;

    float4v acc[8];
#pragma unroll
    for (int nt = 0; nt < 8; ++nt) acc[nt] = (float4v)(0.f);

#pragma unroll 1
    for (int kc = 0; kc < 128; kc += 32) {
        short8 a = *(const short8*)&ht[(wm + col) * 136 + kc + quad * 8];
#pragma unroll
        for (int nt = 0; nt < 8; ++nt) {
            short8 b = *(const short8*)&Wtg[(nt * 16 + col) * 128 + kc + quad * 8];
            acc[nt] = __builtin_amdgcn_mfma_f32_16x16x32_bf16(a, b, acc[nt], 0, 0, 0);
        }
    }

    // C/D layout: col=lane&15, row=quad*4+reg (m89/m91-verified)
    float ps[4] = {0.f, 0.f, 0.f, 0.f}, pd[4] = {0.f, 0.f, 0.f, 0.f};
#pragma unroll
    for (int nt = 0; nt < 8; ++nt) {
        float aL = attn[nt * 16 + col];
        float aR = attn[D + nt * 16 + col];
#pragma unroll
        for (int reg = 0; reg < 4; ++reg) {
            float v = acc[nt][reg];
            ps[reg] = fmaf(v, aL, ps[reg]);
            pd[reg] = fmaf(v, aR, pd[reg]);
            ht[(wm + quad * 4 + reg) * 136 + nt * 16 + col] = f2bf(v);
        }
    }
#pragma unroll
    for (int reg = 0; reg < 4; ++reg) {
#pragma unroll
        for (int off = 1; off < 16; off <<= 1) {
            ps[reg] += __shfl_xor(ps[reg], off);
            pd[reg] += __shfl_xor(pd[reg], off);
        }
        int grow = base + wm + quad * 4 + reg;
        if (col == 0 && grow < N) { s_src[grow] = ps[reg]; s_dst[grow] = pd[reg]; }
    }
    __syncthreads();

#pragma unroll
    for (int it = 0; it < 4; ++it) {
        int idx = it * 256 + tid;
        int r = idx >> 4, c8 = idx & 15;
        if (base + r < N)
            *(uint4*)&zb[(size_t)(base + r) * D + c8 * 8] = *(uint4*)&ht[r * 136 + c8 * 8];
    }
}

// ---------------------------------------------------------------------------
// Atomic-free two-level counting sort of edges by dst.
// hi = dst>>8 (nhi bins), lo = dst&255. Payload = src | et<<16 | lo<<23.
// ---------------------------------------------------------------------------

// A: per-chunk hi-bin histograms -> hist matrix [chunk][bin] (coalesced stores)
__global__ __launch_bounds__(256) void binA_kernel(
    const int* __restrict__ dst, int* __restrict__ histm, int nhi, int E)
{
    __shared__ int hist[256];
    const int tid = threadIdx.x;
    hist[tid] = 0;
    __syncthreads();
    const int base = blockIdx.x * CHUNK;
#pragma unroll
    for (int it = 0; it < CHUNK / 256; ++it) {
        int i = base + it * 256 + tid;
        if (i < E) atomicAdd(&hist[dst[i] >> 8], 1);
    }
    __syncthreads();
    if (tid < nhi) histm[blockIdx.x * nhi + tid] = hist[tid];
}

// B: in-place column prefix over chunks + bin_base scan. One block.
__global__ __launch_bounds__(256) void binB_kernel(
    int* __restrict__ histm, int* __restrict__ bin_base, int nhi, int nchunk)
{
    __shared__ int sc[256];
    const int t = threadIdx.x;
    int total = 0;
    if (t < nhi) {
        for (int c = 0; c < nchunk; ++c) {
            int v = histm[c * nhi + t];
            histm[c * nhi + t] = total;  // exclusive per-chunk prefix within bin
            total += v;
        }
    }
    sc[t] = total;
    __syncthreads();
    for (int off = 1; off < 256; off <<= 1) {
        int u = (t >= off) ? sc[t - off] : 0;
        __syncthreads();
        sc[t] += u;
        __syncthreads();
    }
    if (t < nhi) {
        bin_base[t] = sc[t] - total;           // exclusive bin prefix
        if (t == nhi - 1) bin_base[nhi] = sc[t];  // == E
    }
}

// C: place edges into hi-binned array via LDS cursors (no global atomics)
__global__ __launch_bounds__(256) void binC_kernel(
    const int* __restrict__ src, const int* __restrict__ dst,
    const int* __restrict__ etype, const int* __restrict__ histm,
    const int* __restrict__ bin_base, uint* __restrict__ binned, int nhi, int E)
{
    __shared__ int cursor[256];
    const int tid = threadIdx.x;
    if (tid < nhi) cursor[tid] = bin_base[tid] + histm[blockIdx.x * nhi + tid];
    __syncthreads();
    const int base = blockIdx.x * CHUNK;
#pragma unroll
    for (int it = 0; it < CHUNK / 256; ++it) {
        int i = base + it * 256 + tid;
        if (i < E) {
            int d = dst[i];
            int pos = atomicAdd(&cursor[d >> 8], 1);
            binned[pos] = (uint)src[i] | ((uint)etype[i] << 16) | ((uint)(d & 255) << 23);
        }
    }
}

// D: one block per hi-bin: lo-histogram + LDS scan -> offsets[] and final CSR
__global__ __launch_bounds__(256) void binD_kernel(
    const uint* __restrict__ binned, const int* __restrict__ bin_base,
    int* __restrict__ offsets, uint* __restrict__ csr, int N, int E)
{
    __shared__ int hist[256];
    __shared__ int cursor[256];
    const int t = threadIdx.x;
    const int hi = blockIdx.x;
    const int bb = bin_base[hi];
    const int be = bin_base[hi + 1];
    hist[t] = 0;
    __syncthreads();
    for (int i = bb + t; i < be; i += 256)
        atomicAdd(&hist[(binned[i] >> 23) & 0xFF], 1);
    __syncthreads();
    int total = hist[t];
    int sc = total;
    // inclusive scan in LDS (reuse cursor as scratch)
    cursor[t] = sc;
    __syncthreads();
    for (int off = 1; off < 256; off <<= 1) {
        int u = (t >= off) ? cursor[t - off] : 0;
        __syncthreads();
        cursor[t] += u;
        __syncthreads();
    }
    int excl = cursor[t] - total;
    int node = hi * 256 + t;
    if (node < N) offsets[node] = bb + excl;
    if (node == N - 1 || (hi == gridDim.x - 1 && t == 255)) offsets[N] = E;
    __syncthreads();
    cursor[t] = bb + excl;
    __syncthreads();
    for (int i = bb + t; i < be; i += 256) {
        uint pk = binned[i];
        int pos = atomicAdd(&cursor[(pk >> 23) & 0xFF], 1);
        csr[pos] = pk;
    }
}

// ---------------------------------------------------------------------------
// Aggregate: one wave per dst node; online softmax + weighted bf16-z gather.
// ---------------------------------------------------------------------------
__global__ __launch_bounds__(256) void aggregate_kernel(
    const uint* __restrict__ zb32, const float* __restrict__ s_src,
    const float* __restrict__ s_dst, const int* __restrict__ offsets,
    const uint* __restrict__ csr_packed, const float* __restrict__ rel_emb,
    float* __restrict__ out, int N, int R)
{
    __shared__ float rel_l[128];
    const int tid = threadIdx.x;
    if (tid < R) rel_l[tid] = (tid == 0) ? 0.f : rel_emb[tid];  // padding_idx=0
    __syncthreads();

    const int lane = tid & 63;
    const int d = blockIdx.x * 4 + (tid >> 6);
    if (d >= N) return;

    const int start = offsets[d];
    const int end = offsets[d + 1];
    const float sdst = s_dst[d];

    float m = -INFINITY, l = 0.f;
    float2 acc = make_float2(0.f, 0.f);

    for (int base = start; base < end; base += 64) {
        const int idx = base + lane;
        const bool valid = idx < end;
        const uint packed = valid ? csr_packed[idx] : 0;
        const int srcv = (int)(packed & 0xFFFF);
        const int et = (int)((packed >> 16) & 0x7F);
        float ev = -INFINITY;
        if (valid) {
            float x = s_src[srcv] + sdst;
            ev = (x > 0.f) ? x : 0.01f * x;  // leaky_relu slope 0.01
        }
        float cm = ev;
#pragma unroll
        for (int off = 32; off; off >>= 1) cm = fmaxf(cm, __shfl_xor(cm, off));
        const float newm = fmaxf(m, cm);
        const float scale = __expf(m - newm);
        const float p = valid ? __expf(ev - newm) : 0.f;
        float ssum = p;
#pragma unroll
        for (int off = 32; off; off >>= 1) ssum += __shfl_xor(ssum, off);
        l = l * scale + ssum;
        acc.x *= scale;
        acc.y *= scale;
        m = newm;

        const float w = valid ? p * rel_l[et] : 0.f;
        const int nv = min(64, end - base);
        int j = 0;
        for (; j + 1 < nv; j += 2) {
            const float w0 = __shfl(w, j);
            const float w1 = __shfl(w, j + 1);
            const int s0 = __shfl(srcv, j);
            const int s1 = __shfl(srcv, j + 1);
            const uint u0 = zb32[(size_t)s0 * 64 + lane];
            const uint u1 = zb32[(size_t)s1 * 64 + lane];
            acc.x = fmaf(w0, __uint_as_float(u0 << 16), acc.x);
            acc.y = fmaf(w0, __uint_as_float(u0 & 0xFFFF0000u), acc.y);
            acc.x = fmaf(w1, __uint_as_float(u1 << 16), acc.x);
            acc.y = fmaf(w1, __uint_as_float(u1 & 0xFFFF0000u), acc.y);
        }
        if (j < nv) {
            const float wj = __shfl(w, j);
            const int sj = __shfl(srcv, j);
            const uint u = zb32[(size_t)sj * 64 + lane];
            acc.x = fmaf(wj, __uint_as_float(u << 16), acc.x);
            acc.y = fmaf(wj, __uint_as_float(u & 0xFFFF0000u), acc.y);
        }
    }

    const float inv = (l > 0.f) ? 1.0f / l : 0.f;
    float2 res = make_float2(acc.x * inv, acc.y * inv);
    *(float2*)(out + (size_t)d * D + 2 * lane) = res;
}

// ---------------------------------------------------------------------------
extern "C" void kernel_launch(void* const* d_in, const int* in_sizes, int n_in,
                              void* d_out, int out_size, void* d_ws, size_t ws_size,
                              hipStream_t stream)
{
    const float* h    = (const float*)d_in[0];
    const float* W    = (const float*)d_in[1];
    const float* attn = (const float*)d_in[2];
    const float* rel  = (const float*)d_in[3];
    const int*   src  = (const int*)d_in[4];
    const int*   dst  = (const int*)d_in[5];
    const int*   et   = (const int*)d_in[6];
    float* out = (float*)d_out;

    const int N = in_sizes[0] / D;   // 50000
    const int E = in_sizes[4];       // 800000
    const int R = in_sizes[3];       // 100

    char* p = (char*)d_ws;
    auto alloc = [&](size_t bytes) {
        char* q = p;
        p += (bytes + 255) & ~(size_t)255;
        return q;
    };
    const int nhi    = (N + 255) / 256;        // 196
    const int nchunk = (E + CHUNK - 1) / CHUNK; // 196

    ushort* zb      = (ushort*)alloc((size_t)N * D * sizeof(ushort));  // 12.8 MB
    ushort* Wtg     = (ushort*)alloc((size_t)D * D * sizeof(ushort));  // 32 KB
    float* ssrc     = (float*)alloc((size_t)N * sizeof(float));
    float* sdst     = (float*)alloc((size_t)N * sizeof(float));
    int*   offsets  = (int*)alloc((size_t)(N + 1) * sizeof(int));
    uint*  binned   = (uint*)alloc((size_t)E * sizeof(uint));          // 3.2 MB
    uint*  csr      = (uint*)alloc((size_t)E * sizeof(uint));          // 3.2 MB
    int*   histm    = (int*)alloc((size_t)nchunk * nhi * sizeof(int)); // 154 KB
    int*   bin_base = (int*)alloc((size_t)(nhi + 1) * sizeof(int));

    const int gblocks = (N + GROWS - 1) / GROWS;  // 782

    convW_kernel<<<64, 256, 0, stream>>>(W, Wtg);
    gemm_mfma_kernel<<<gblocks, 256, 0, stream>>>(h, Wtg, attn, zb, ssrc, sdst, N);
    binA_kernel<<<nchunk, 256, 0, stream>>>(dst, histm, nhi, E);
    binB_kernel<<<1, 256, 0, stream>>>(histm, bin_base, nhi, nchunk);
    binC_kernel<<<nchunk, 256, 0, stream>>>(src, dst, et, histm, bin_base, binned, nhi, E);
    binD_kernel<<<nhi, 256, 0, stream>>>(binned, bin_base, offsets, csr, N, E);
    aggregate_kernel<<<(N + 3) / 4, 256, 0, stream>>>((const uint*)zb, ssrc, sdst,
                                                      offsets, csr, rel, out, N, R);
}

// Round 6
// 189.857 us; speedup vs baseline: 1.2161x; 1.2161x over previous
//
#include <hip/hip_runtime.h>

#define D 128
#define GROWS 64
#define CHUNK 4096

typedef __attribute__((ext_vector_type(8))) short short8;
typedef __attribute__((ext_vector_type(4))) float float4v;

// round-to-nearest-even fp32 -> bf16
__device__ __forceinline__ ushort f2bf(float x) {
    uint u = __float_as_uint(x);
    return (ushort)((u + 0x7FFFu + ((u >> 16) & 1u)) >> 16);
}

// ---------------------------------------------------------------------------
// Kernel 0: one-time W convert+transpose: Wtg[n*128+k] = bf16(W[k*128+n]).
// ---------------------------------------------------------------------------
__global__ __launch_bounds__(256) void convW_kernel(
    const float* __restrict__ W, ushort* __restrict__ Wtg)
{
    int idx = blockIdx.x * 256 + threadIdx.x;  // 16384 total
    int k = idx >> 7, n = idx & 127;
    Wtg[n * 128 + k] = f2bf(W[idx]);
}

// ---------------------------------------------------------------------------
// Kernel 1: z = h @ W via bf16 MFMA (16x16x32). B-fragments from global Wtg
// (32 KB, L1-hot). LDS h-tile (17 KB, stride 136) reused to stage bf16 z for
// coalesced uint4 writeback. Fused s_src/s_dst epilogue. No atomics.
// ---------------------------------------------------------------------------
__global__ __launch_bounds__(256) void gemm_mfma_kernel(
    const float* __restrict__ h, const ushort* __restrict__ Wtg,
    const float* __restrict__ attn,
    ushort* __restrict__ zb, float* __restrict__ s_src, float* __restrict__ s_dst,
    int N)
{
    __shared__ ushort ht[GROWS * 136];  // h-tile, then z-tile
    const int tid = threadIdx.x;
    const int base = blockIdx.x * GROWS;

#pragma unroll
    for (int it = 0; it < 8; ++it) {
        int idx = it * 256 + tid;
        int r = idx >> 5, c4 = (idx & 31) * 4;
        float4 v = make_float4(0.f, 0.f, 0.f, 0.f);
        if (base + r < N) v = *(const float4*)&h[(size_t)(base + r) * D + c4];
        ushort4 u = make_ushort4(f2bf(v.x), f2bf(v.y), f2bf(v.z), f2bf(v.w));
        *(ushort4*)&ht[r * 136 + c4] = u;
    }
    __syncthreads();

    const int lane = tid & 63;
    const int wave = tid >> 6;
    const int col = lane & 15;
    const int quad = lane >> 4;
    const int wm = wave * 16;

    float4v acc[8];
#pragma unroll
    for (int nt = 0; nt < 8; ++nt) acc[nt] = (float4v)(0.f);

#pragma unroll 1
    for (int kc = 0; kc < 128; kc += 32) {
        short8 a = *(const short8*)&ht[(wm + col) * 136 + kc + quad * 8];
#pragma unroll
        for (int nt = 0; nt < 8; ++nt) {
            short8 b = *(const short8*)&Wtg[(nt * 16 + col) * 128 + kc + quad * 8];
            acc[nt] = __builtin_amdgcn_mfma_f32_16x16x32_bf16(a, b, acc[nt], 0, 0, 0);
        }
    }

    // C/D layout: col=lane&15, row=quad*4+reg (m89/m91-verified)
    float ps[4] = {0.f, 0.f, 0.f, 0.f}, pd[4] = {0.f, 0.f, 0.f, 0.f};
#pragma unroll
    for (int nt = 0; nt < 8; ++nt) {
        float aL = attn[nt * 16 + col];
        float aR = attn[D + nt * 16 + col];
#pragma unroll
        for (int reg = 0; reg < 4; ++reg) {
            float v = acc[nt][reg];
            ps[reg] = fmaf(v, aL, ps[reg]);
            pd[reg] = fmaf(v, aR, pd[reg]);
            ht[(wm + quad * 4 + reg) * 136 + nt * 16 + col] = f2bf(v);
        }
    }
#pragma unroll
    for (int reg = 0; reg < 4; ++reg) {
#pragma unroll
        for (int off = 1; off < 16; off <<= 1) {
            ps[reg] += __shfl_xor(ps[reg], off);
            pd[reg] += __shfl_xor(pd[reg], off);
        }
        int grow = base + wm + quad * 4 + reg;
        if (col == 0 && grow < N) { s_src[grow] = ps[reg]; s_dst[grow] = pd[reg]; }
    }
    __syncthreads();

#pragma unroll
    for (int it = 0; it < 4; ++it) {
        int idx = it * 256 + tid;
        int r = idx >> 4, c8 = idx & 15;
        if (base + r < N)
            *(uint4*)&zb[(size_t)(base + r) * D + c8 * 8] = *(uint4*)&ht[r * 136 + c8 * 8];
    }
}

// ---------------------------------------------------------------------------
// Atomic-free two-level counting sort of edges by dst.
// hi = dst>>8 (nhi bins), lo = dst&255. Payload = src | et<<16 | lo<<23.
// ---------------------------------------------------------------------------

// A: per-chunk hi-bin histograms -> hist matrix [chunk][bin]
__global__ __launch_bounds__(256) void binA_kernel(
    const int* __restrict__ dst, int* __restrict__ histm, int nhi, int E)
{
    __shared__ int hist[256];
    const int tid = threadIdx.x;
    hist[tid] = 0;
    __syncthreads();
    const int base = blockIdx.x * CHUNK;
#pragma unroll
    for (int it = 0; it < CHUNK / 256; ++it) {
        int i = base + it * 256 + tid;
        if (i < E) atomicAdd(&hist[dst[i] >> 8], 1);
    }
    __syncthreads();
    if (tid < nhi) histm[blockIdx.x * nhi + tid] = hist[tid];
}

// B1: one block (64 lanes) per bin: exclusive prefix of that bin's column
// over chunks (in place), column total -> colsum. Loads are latency-parallel.
__global__ __launch_bounds__(64) void binB1_kernel(
    int* __restrict__ histm, int* __restrict__ colsum, int nhi, int nchunk)
{
    const int b = blockIdx.x;       // bin
    const int t = threadIdx.x;      // lane
    const int K = (nchunk + 63) / 64;  // chunks per lane (blocked)
    int v[8];                       // K <= 8 supported
    int s = 0;
#pragma unroll
    for (int j = 0; j < 8; ++j) {
        int c = t * K + j;
        v[j] = (j < K && c < nchunk) ? histm[c * nhi + b] : 0;
        s += v[j];
    }
    // wave exclusive scan of per-lane sums
    int incl = s;
#pragma unroll
    for (int off = 1; off < 64; off <<= 1) {
        int u = __shfl_up(incl, off);
        if (t >= off) incl += u;
    }
    int run = incl - s;  // exclusive prefix for this lane's first chunk
#pragma unroll
    for (int j = 0; j < 8; ++j) {
        int c = t * K + j;
        if (j < K && c < nchunk) { histm[c * nhi + b] = run; run += v[j]; }
    }
    if (t == 63) colsum[b] = incl;  // bin total
}

// B2: single small block: exclusive scan of bin totals -> bin_base[0..nhi]
__global__ __launch_bounds__(256) void binB2_kernel(
    const int* __restrict__ colsum, int* __restrict__ bin_base, int nhi, int E)
{
    __shared__ int sc[256];
    const int t = threadIdx.x;
    int total = (t < nhi) ? colsum[t] : 0;
    sc[t] = total;
    __syncthreads();
    for (int off = 1; off < 256; off <<= 1) {
        int u = (t >= off) ? sc[t - off] : 0;
        __syncthreads();
        sc[t] += u;
        __syncthreads();
    }
    if (t < nhi) bin_base[t] = sc[t] - total;  // exclusive
    if (t == nhi - 1) bin_base[nhi] = sc[t];   // == E
}

// C: place edges into hi-binned array via LDS cursors
__global__ __launch_bounds__(256) void binC_kernel(
    const int* __restrict__ src, const int* __restrict__ dst,
    const int* __restrict__ etype, const int* __restrict__ histm,
    const int* __restrict__ bin_base, uint* __restrict__ binned, int nhi, int E)
{
    __shared__ int cursor[256];
    const int tid = threadIdx.x;
    if (tid < nhi) cursor[tid] = bin_base[tid] + histm[blockIdx.x * nhi + tid];
    __syncthreads();
    const int base = blockIdx.x * CHUNK;
#pragma unroll
    for (int it = 0; it < CHUNK / 256; ++it) {
        int i = base + it * 256 + tid;
        if (i < E) {
            int d = dst[i];
            int pos = atomicAdd(&cursor[d >> 8], 1);
            binned[pos] = (uint)src[i] | ((uint)etype[i] << 16) | ((uint)(d & 255) << 23);
        }
    }
}

// D: one block per hi-bin: lo-histogram + LDS scan -> offsets[] and final CSR
__global__ __launch_bounds__(256) void binD_kernel(
    const uint* __restrict__ binned, const int* __restrict__ bin_base,
    int* __restrict__ offsets, uint* __restrict__ csr, int N, int E)
{
    __shared__ int hist[256];
    __shared__ int cursor[256];
    const int t = threadIdx.x;
    const int hi = blockIdx.x;
    const int bb = bin_base[hi];
    const int be = bin_base[hi + 1];
    hist[t] = 0;
    __syncthreads();
    for (int i = bb + t; i < be; i += 256)
        atomicAdd(&hist[(binned[i] >> 23) & 0xFF], 1);
    __syncthreads();
    int total = hist[t];
    cursor[t] = total;
    __syncthreads();
    for (int off = 1; off < 256; off <<= 1) {
        int u = (t >= off) ? cursor[t - off] : 0;
        __syncthreads();
        cursor[t] += u;
        __syncthreads();
    }
    int excl = cursor[t] - total;
    int node = hi * 256 + t;
    if (node < N) offsets[node] = bb + excl;
    if (node == N - 1 || (hi == gridDim.x - 1 && t == 255)) offsets[N] = E;
    __syncthreads();
    cursor[t] = bb + excl;
    __syncthreads();
    for (int i = bb + t; i < be; i += 256) {
        uint pk = binned[i];
        int pos = atomicAdd(&cursor[(pk >> 23) & 0xFF], 1);
        csr[pos] = pk;
    }
}

// ---------------------------------------------------------------------------
// Aggregate: one wave per dst node; online softmax + weighted bf16-z gather.
// ---------------------------------------------------------------------------
__global__ __launch_bounds__(256) void aggregate_kernel(
    const uint* __restrict__ zb32, const float* __restrict__ s_src,
    const float* __restrict__ s_dst, const int* __restrict__ offsets,
    const uint* __restrict__ csr_packed, const float* __restrict__ rel_emb,
    float* __restrict__ out, int N, int R)
{
    __shared__ float rel_l[128];
    const int tid = threadIdx.x;
    if (tid < R) rel_l[tid] = (tid == 0) ? 0.f : rel_emb[tid];  // padding_idx=0
    __syncthreads();

    const int lane = tid & 63;
    const int d = blockIdx.x * 4 + (tid >> 6);
    if (d >= N) return;

    const int start = offsets[d];
    const int end = offsets[d + 1];
    const float sdst = s_dst[d];

    float m = -INFINITY, l = 0.f;
    float2 acc = make_float2(0.f, 0.f);

    for (int base = start; base < end; base += 64) {
        const int idx = base + lane;
        const bool valid = idx < end;
        const uint packed = valid ? csr_packed[idx] : 0;
        const int srcv = (int)(packed & 0xFFFF);
        const int et = (int)((packed >> 16) & 0x7F);
        float ev = -INFINITY;
        if (valid) {
            float x = s_src[srcv] + sdst;
            ev = (x > 0.f) ? x : 0.01f * x;  // leaky_relu slope 0.01
        }
        float cm = ev;
#pragma unroll
        for (int off = 32; off; off >>= 1) cm = fmaxf(cm, __shfl_xor(cm, off));
        const float newm = fmaxf(m, cm);
        const float scale = __expf(m - newm);
        const float p = valid ? __expf(ev - newm) : 0.f;
        float ssum = p;
#pragma unroll
        for (int off = 32; off; off >>= 1) ssum += __shfl_xor(ssum, off);
        l = l * scale + ssum;
        acc.x *= scale;
        acc.y *= scale;
        m = newm;

        const float w = valid ? p * rel_l[et] : 0.f;
        const int nv = min(64, end - base);
        int j = 0;
        for (; j + 1 < nv; j += 2) {
            const float w0 = __shfl(w, j);
            const float w1 = __shfl(w, j + 1);
            const int s0 = __shfl(srcv, j);
            const int s1 = __shfl(srcv, j + 1);
            const uint u0 = zb32[(size_t)s0 * 64 + lane];
            const uint u1 = zb32[(size_t)s1 * 64 + lane];
            acc.x = fmaf(w0, __uint_as_float(u0 << 16), acc.x);
            acc.y = fmaf(w0, __uint_as_float(u0 & 0xFFFF0000u), acc.y);
            acc.x = fmaf(w1, __uint_as_float(u1 << 16), acc.x);
            acc.y = fmaf(w1, __uint_as_float(u1 & 0xFFFF0000u), acc.y);
        }
        if (j < nv) {
            const float wj = __shfl(w, j);
            const int sj = __shfl(srcv, j);
            const uint u = zb32[(size_t)sj * 64 + lane];
            acc.x = fmaf(wj, __uint_as_float(u << 16), acc.x);
            acc.y = fmaf(wj, __uint_as_float(u & 0xFFFF0000u), acc.y);
        }
    }

    const float inv = (l > 0.f) ? 1.0f / l : 0.f;
    float2 res = make_float2(acc.x * inv, acc.y * inv);
    *(float2*)(out + (size_t)d * D + 2 * lane) = res;
}

// ---------------------------------------------------------------------------
extern "C" void kernel_launch(void* const* d_in, const int* in_sizes, int n_in,
                              void* d_out, int out_size, void* d_ws, size_t ws_size,
                              hipStream_t stream)
{
    const float* h    = (const float*)d_in[0];
    const float* W    = (const float*)d_in[1];
    const float* attn = (const float*)d_in[2];
    const float* rel  = (const float*)d_in[3];
    const int*   src  = (const int*)d_in[4];
    const int*   dst  = (const int*)d_in[5];
    const int*   et   = (const int*)d_in[6];
    float* out = (float*)d_out;

    const int N = in_sizes[0] / D;   // 50000
    const int E = in_sizes[4];       // 800000
    const int R = in_sizes[3];       // 100

    char* p = (char*)d_ws;
    auto alloc = [&](size_t bytes) {
        char* q = p;
        p += (bytes + 255) & ~(size_t)255;
        return q;
    };
    const int nhi    = (N + 255) / 256;         // 196
    const int nchunk = (E + CHUNK - 1) / CHUNK; // 196

    ushort* zb      = (ushort*)alloc((size_t)N * D * sizeof(ushort));  // 12.8 MB
    ushort* Wtg     = (ushort*)alloc((size_t)D * D * sizeof(ushort));  // 32 KB
    float* ssrc     = (float*)alloc((size_t)N * sizeof(float));
    float* sdst     = (float*)alloc((size_t)N * sizeof(float));
    int*   offsets  = (int*)alloc((size_t)(N + 1) * sizeof(int));
    uint*  binned   = (uint*)alloc((size_t)E * sizeof(uint));          // 3.2 MB
    uint*  csr      = (uint*)alloc((size_t)E * sizeof(uint));          // 3.2 MB
    int*   histm    = (int*)alloc((size_t)nchunk * nhi * sizeof(int)); // 154 KB
    int*   colsum   = (int*)alloc((size_t)nhi * sizeof(int));
    int*   bin_base = (int*)alloc((size_t)(nhi + 1) * sizeof(int));

    const int gblocks = (N + GROWS - 1) / GROWS;  // 782

    convW_kernel<<<64, 256, 0, stream>>>(W, Wtg);
    gemm_mfma_kernel<<<gblocks, 256, 0, stream>>>(h, Wtg, attn, zb, ssrc, sdst, N);
    binA_kernel<<<nchunk, 256, 0, stream>>>(dst, histm, nhi, E);
    binB1_kernel<<<nhi, 64, 0, stream>>>(histm, colsum, nhi, nchunk);
    binB2_kernel<<<1, 256, 0, stream>>>(colsum, bin_base, nhi, E);
    binC_kernel<<<nchunk, 256, 0, stream>>>(src, dst, et, histm, bin_base, binned, nhi, E);
    binD_kernel<<<nhi, 256, 0, stream>>>(binned, bin_base, offsets, csr, N, E);
    aggregate_kernel<<<(N + 3) / 4, 256, 0, stream>>>((const uint*)zb, ssrc, sdst,
                                                      offsets, csr, rel, out, N, R);
}

// Round 7
// 179.410 us; speedup vs baseline: 1.2870x; 1.0582x over previous
//
#include <hip/hip_runtime.h>

#define D 128
#define GROWS 64
#define CHUNK 4096

typedef __attribute__((ext_vector_type(8))) short short8;
typedef __attribute__((ext_vector_type(4))) float float4v;

// round-to-nearest-even fp32 -> bf16
__device__ __forceinline__ ushort f2bf(float x) {
    uint u = __float_as_uint(x);
    return (ushort)((u + 0x7FFFu + ((u >> 16) & 1u)) >> 16);
}
__device__ __forceinline__ float bf_lo(uint u) { return __uint_as_float(u << 16); }
__device__ __forceinline__ float bf_hi(uint u) { return __uint_as_float(u & 0xFFFF0000u); }

// ---------------------------------------------------------------------------
// Kernel 0: one-time W convert+transpose: Wtg[n*128+k] = bf16(W[k*128+n]).
// ---------------------------------------------------------------------------
__global__ __launch_bounds__(256) void convW_kernel(
    const float* __restrict__ W, ushort* __restrict__ Wtg)
{
    int idx = blockIdx.x * 256 + threadIdx.x;  // 16384 total
    int k = idx >> 7, n = idx & 127;
    Wtg[n * 128 + k] = f2bf(W[idx]);
}

// ---------------------------------------------------------------------------
// Kernel 1: z = h @ W via bf16 MFMA (16x16x32). 512-thread blocks, 8 waves:
// wave (wr,wc) computes rows [16wr,16wr+16) x cols [64wc,64wc+64).
// B-fragments from global Wtg (32 KB, L1-hot). LDS h-tile (17 KB, stride 136)
// reused to stage bf16 z for coalesced uint4 writeback. Fused s_src/s_dst.
// ---------------------------------------------------------------------------
__global__ __launch_bounds__(512) void gemm_mfma_kernel(
    const float* __restrict__ h, const ushort* __restrict__ Wtg,
    const float* __restrict__ attn,
    ushort* __restrict__ zb, float* __restrict__ s_src, float* __restrict__ s_dst,
    int N)
{
    __shared__ ushort ht[GROWS * 136];   // h-tile, then z-tile
    __shared__ float psum_s[GROWS][2];
    __shared__ float psum_d[GROWS][2];
    const int tid = threadIdx.x;
    const int base = blockIdx.x * GROWS;

    // stage h rows [base, base+64) fp32 -> bf16: 2048 float4-chunks / 512 thr
#pragma unroll
    for (int it = 0; it < 4; ++it) {
        int idx = it * 512 + tid;
        int r = idx >> 5, c4 = (idx & 31) * 4;
        float4 v = make_float4(0.f, 0.f, 0.f, 0.f);
        if (base + r < N) v = *(const float4*)&h[(size_t)(base + r) * D + c4];
        ushort4 u = make_ushort4(f2bf(v.x), f2bf(v.y), f2bf(v.z), f2bf(v.w));
        *(ushort4*)&ht[r * 136 + c4] = u;
    }
    __syncthreads();

    const int lane = tid & 63;
    const int wave = tid >> 6;      // 0..7
    const int wr = wave >> 1;       // row group 0..3
    const int wc = wave & 1;        // col half 0..1
    const int col = lane & 15;
    const int quad = lane >> 4;
    const int wm = wr * 16;

    float4v acc[4];
#pragma unroll
    for (int nt = 0; nt < 4; ++nt) acc[nt] = (float4v)(0.f);

#pragma unroll 1
    for (int kc = 0; kc < 128; kc += 32) {
        short8 a = *(const short8*)&ht[(wm + col) * 136 + kc + quad * 8];
#pragma unroll
        for (int nt = 0; nt < 4; ++nt) {
            short8 b = *(const short8*)&Wtg[(wc * 64 + nt * 16 + col) * 128 + kc + quad * 8];
            acc[nt] = __builtin_amdgcn_mfma_f32_16x16x32_bf16(a, b, acc[nt], 0, 0, 0);
        }
    }
    __syncthreads();  // all A-fragment reads done before z overwrites ht

    // Epilogue: C/D layout col=lane&15, row=quad*4+reg (m89/m91-verified)
    float ps[4] = {0.f, 0.f, 0.f, 0.f}, pd[4] = {0.f, 0.f, 0.f, 0.f};
#pragma unroll
    for (int nt = 0; nt < 4; ++nt) {
        float aL = attn[wc * 64 + nt * 16 + col];
        float aR = attn[D + wc * 64 + nt * 16 + col];
#pragma unroll
        for (int reg = 0; reg < 4; ++reg) {
            float v = acc[nt][reg];
            ps[reg] = fmaf(v, aL, ps[reg]);
            pd[reg] = fmaf(v, aR, pd[reg]);
            ht[(wm + quad * 4 + reg) * 136 + wc * 64 + nt * 16 + col] = f2bf(v);
        }
    }
#pragma unroll
    for (int reg = 0; reg < 4; ++reg) {
#pragma unroll
        for (int off = 1; off < 16; off <<= 1) {
            ps[reg] += __shfl_xor(ps[reg], off);
            pd[reg] += __shfl_xor(pd[reg], off);
        }
        if (col == 0) {
            int rl = wm + quad * 4 + reg;
            psum_s[rl][wc] = ps[reg];
            psum_d[rl][wc] = pd[reg];
        }
    }
    __syncthreads();

    if (tid < GROWS && base + tid < N) {
        s_src[base + tid] = psum_s[tid][0] + psum_s[tid][1];
        s_dst[base + tid] = psum_d[tid][0] + psum_d[tid][1];
    }

    // coalesced z writeback: 1024 uint4-chunks / 512 threads
#pragma unroll
    for (int it = 0; it < 2; ++it) {
        int idx = it * 512 + tid;
        int r = idx >> 4, c8 = idx & 15;
        if (base + r < N)
            *(uint4*)&zb[(size_t)(base + r) * D + c8 * 8] = *(uint4*)&ht[r * 136 + c8 * 8];
    }
}

// ---------------------------------------------------------------------------
// Atomic-free two-level counting sort of edges by dst.
// hi = dst>>8 (nhi bins), lo = dst&255. Payload = src | et<<16 | lo<<23.
// ---------------------------------------------------------------------------

// A: per-chunk hi-bin histograms -> hist matrix [chunk][bin]
__global__ __launch_bounds__(256) void binA_kernel(
    const int* __restrict__ dst, int* __restrict__ histm, int nhi, int E)
{
    __shared__ int hist[256];
    const int tid = threadIdx.x;
    hist[tid] = 0;
    __syncthreads();
    const int base = blockIdx.x * CHUNK;
#pragma unroll
    for (int it = 0; it < CHUNK / 256; ++it) {
        int i = base + it * 256 + tid;
        if (i < E) atomicAdd(&hist[dst[i] >> 8], 1);
    }
    __syncthreads();
    if (tid < nhi) histm[blockIdx.x * nhi + tid] = hist[tid];
}

// B1: one block (64 lanes) per bin: exclusive prefix of that bin's column
// over chunks (in place), column total -> colsum. Loads are latency-parallel.
__global__ __launch_bounds__(64) void binB1_kernel(
    int* __restrict__ histm, int* __restrict__ colsum, int nhi, int nchunk)
{
    const int b = blockIdx.x;
    const int t = threadIdx.x;
    const int K = (nchunk + 63) / 64;
    int v[8];
    int s = 0;
#pragma unroll
    for (int j = 0; j < 8; ++j) {
        int c = t * K + j;
        v[j] = (j < K && c < nchunk) ? histm[c * nhi + b] : 0;
        s += v[j];
    }
    int incl = s;
#pragma unroll
    for (int off = 1; off < 64; off <<= 1) {
        int u = __shfl_up(incl, off);
        if (t >= off) incl += u;
    }
    int run = incl - s;
#pragma unroll
    for (int j = 0; j < 8; ++j) {
        int c = t * K + j;
        if (j < K && c < nchunk) { histm[c * nhi + b] = run; run += v[j]; }
    }
    if (t == 63) colsum[b] = incl;
}

// B2: single small block: exclusive scan of bin totals -> bin_base[0..nhi]
__global__ __launch_bounds__(256) void binB2_kernel(
    const int* __restrict__ colsum, int* __restrict__ bin_base, int nhi, int E)
{
    __shared__ int sc[256];
    const int t = threadIdx.x;
    int total = (t < nhi) ? colsum[t] : 0;
    sc[t] = total;
    __syncthreads();
    for (int off = 1; off < 256; off <<= 1) {
        int u = (t >= off) ? sc[t - off] : 0;
        __syncthreads();
        sc[t] += u;
        __syncthreads();
    }
    if (t < nhi) bin_base[t] = sc[t] - total;
    if (t == nhi - 1) bin_base[nhi] = sc[t];
}

// C: place edges into hi-binned array via LDS cursors
__global__ __launch_bounds__(256) void binC_kernel(
    const int* __restrict__ src, const int* __restrict__ dst,
    const int* __restrict__ etype, const int* __restrict__ histm,
    const int* __restrict__ bin_base, uint* __restrict__ binned, int nhi, int E)
{
    __shared__ int cursor[256];
    const int tid = threadIdx.x;
    if (tid < nhi) cursor[tid] = bin_base[tid] + histm[blockIdx.x * nhi + tid];
    __syncthreads();
    const int base = blockIdx.x * CHUNK;
#pragma unroll
    for (int it = 0; it < CHUNK / 256; ++it) {
        int i = base + it * 256 + tid;
        if (i < E) {
            int d = dst[i];
            int pos = atomicAdd(&cursor[d >> 8], 1);
            binned[pos] = (uint)src[i] | ((uint)etype[i] << 16) | ((uint)(d & 255) << 23);
        }
    }
}

// D: one block per hi-bin: lo-histogram + LDS scan -> offsets[] and final CSR
__global__ __launch_bounds__(256) void binD_kernel(
    const uint* __restrict__ binned, const int* __restrict__ bin_base,
    int* __restrict__ offsets, uint* __restrict__ csr, int N, int E)
{
    __shared__ int hist[256];
    __shared__ int cursor[256];
    const int t = threadIdx.x;
    const int hi = blockIdx.x;
    const int bb = bin_base[hi];
    const int be = bin_base[hi + 1];
    hist[t] = 0;
    __syncthreads();
    for (int i = bb + t; i < be; i += 256)
        atomicAdd(&hist[(binned[i] >> 23) & 0xFF], 1);
    __syncthreads();
    int total = hist[t];
    cursor[t] = total;
    __syncthreads();
    for (int off = 1; off < 256; off <<= 1) {
        int u = (t >= off) ? cursor[t - off] : 0;
        __syncthreads();
        cursor[t] += u;
        __syncthreads();
    }
    int excl = cursor[t] - total;
    int node = hi * 256 + t;
    if (node < N) offsets[node] = bb + excl;
    if (node == N - 1 || (hi == gridDim.x - 1 && t == 255)) offsets[N] = E;
    __syncthreads();
    cursor[t] = bb + excl;
    __syncthreads();
    for (int i = bb + t; i < be; i += 256) {
        uint pk = binned[i];
        int pos = atomicAdd(&cursor[(pk >> 23) & 0xFF], 1);
        csr[pos] = pk;
    }
}

// ---------------------------------------------------------------------------
// Aggregate: one wave per dst node; online softmax + weighted bf16-z gather.
// Accumulate phase processes 2 edges per step via lane halves (lanes 0-31 =
// even edge, 32-63 = odd edge; each lane covers 4 cols via uint2), unrolled
// x2 (4 edges in flight). Final shfl_xor(32) merges the halves.
// ---------------------------------------------------------------------------
__global__ __launch_bounds__(256) void aggregate_kernel(
    const uint* __restrict__ zb32, const float* __restrict__ s_src,
    const float* __restrict__ s_dst, const int* __restrict__ offsets,
    const uint* __restrict__ csr_packed, const float* __restrict__ rel_emb,
    float* __restrict__ out, int N, int R)
{
    __shared__ float rel_l[128];
    const int tid = threadIdx.x;
    if (tid < R) rel_l[tid] = (tid == 0) ? 0.f : rel_emb[tid];  // padding_idx=0
    __syncthreads();

    const int lane = tid & 63;
    const int half = lane & 31;   // col group: cols [4*half, 4*half+4)
    const int hsel = lane >> 5;   // 0: even edge, 1: odd edge
    const int d = blockIdx.x * 4 + (tid >> 6);
    if (d >= N) return;

    const int start = offsets[d];
    const int end = offsets[d + 1];
    const float sdst = s_dst[d];

    float m = -INFINITY, l = 0.f;
    float4 acc = make_float4(0.f, 0.f, 0.f, 0.f);

    for (int base = start; base < end; base += 64) {
        const int idx = base + lane;
        const bool valid = idx < end;
        const uint packed = valid ? csr_packed[idx] : 0;
        const int srcv = (int)(packed & 0xFFFF);
        const int et = (int)((packed >> 16) & 0x7F);
        float ev = -INFINITY;
        if (valid) {
            float x = s_src[srcv] + sdst;
            ev = (x > 0.f) ? x : 0.01f * x;  // leaky_relu slope 0.01
        }
        float cm = ev;
#pragma unroll
        for (int off = 32; off; off >>= 1) cm = fmaxf(cm, __shfl_xor(cm, off));
        const float newm = fmaxf(m, cm);
        const float scale = __expf(m - newm);
        const float p = valid ? __expf(ev - newm) : 0.f;  // 0 for invalid lanes
        float ssum = p;
#pragma unroll
        for (int off = 32; off; off >>= 1) ssum += __shfl_xor(ssum, off);
        l = l * scale + ssum;
        acc.x *= scale; acc.y *= scale; acc.z *= scale; acc.w *= scale;
        m = newm;

        const float w = p * rel_l[et];  // 0 for invalid (p=0)
        const int nv = min(64, end - base);
        for (int j = 0; j < nv; j += 4) {
            // e0,e1 <= 63 always (j <= 60); w==0 for invalid edges -> safe
            const int e0 = j + hsel, e1 = j + 2 + hsel;
            const float w0 = __shfl(w, e0);
            const float w1 = __shfl(w, e1);
            const int s0 = __shfl(srcv, e0);
            const int s1 = __shfl(srcv, e1);
            const uint2 u0 = *(const uint2*)(zb32 + (size_t)s0 * 64 + half * 2);
            const uint2 u1 = *(const uint2*)(zb32 + (size_t)s1 * 64 + half * 2);
            acc.x = fmaf(w0, bf_lo(u0.x), acc.x);
            acc.y = fmaf(w0, bf_hi(u0.x), acc.y);
            acc.z = fmaf(w0, bf_lo(u0.y), acc.z);
            acc.w = fmaf(w0, bf_hi(u0.y), acc.w);
            acc.x = fmaf(w1, bf_lo(u1.x), acc.x);
            acc.y = fmaf(w1, bf_hi(u1.x), acc.y);
            acc.z = fmaf(w1, bf_lo(u1.y), acc.z);
            acc.w = fmaf(w1, bf_hi(u1.y), acc.w);
        }
    }

    // merge even/odd halves
    acc.x += __shfl_xor(acc.x, 32);
    acc.y += __shfl_xor(acc.y, 32);
    acc.z += __shfl_xor(acc.z, 32);
    acc.w += __shfl_xor(acc.w, 32);

    const float inv = (l > 0.f) ? 1.0f / l : 0.f;  // no-edge nodes -> 0
    if (lane < 32) {
        float4 res = make_float4(acc.x * inv, acc.y * inv, acc.z * inv, acc.w * inv);
        *(float4*)(out + (size_t)d * D + 4 * half) = res;
    }
}

// ---------------------------------------------------------------------------
extern "C" void kernel_launch(void* const* d_in, const int* in_sizes, int n_in,
                              void* d_out, int out_size, void* d_ws, size_t ws_size,
                              hipStream_t stream)
{
    const float* h    = (const float*)d_in[0];
    const float* W    = (const float*)d_in[1];
    const float* attn = (const float*)d_in[2];
    const float* rel  = (const float*)d_in[3];
    const int*   src  = (const int*)d_in[4];
    const int*   dst  = (const int*)d_in[5];
    const int*   et   = (const int*)d_in[6];
    float* out = (float*)d_out;

    const int N = in_sizes[0] / D;   // 50000
    const int E = in_sizes[4];       // 800000
    const int R = in_sizes[3];       // 100

    char* p = (char*)d_ws;
    auto alloc = [&](size_t bytes) {
        char* q = p;
        p += (bytes + 255) & ~(size_t)255;
        return q;
    };
    const int nhi    = (N + 255) / 256;         // 196
    const int nchunk = (E + CHUNK - 1) / CHUNK; // 196

    ushort* zb      = (ushort*)alloc((size_t)N * D * sizeof(ushort));  // 12.8 MB
    ushort* Wtg     = (ushort*)alloc((size_t)D * D * sizeof(ushort));  // 32 KB
    float* ssrc     = (float*)alloc((size_t)N * sizeof(float));
    float* sdst     = (float*)alloc((size_t)N * sizeof(float));
    int*   offsets  = (int*)alloc((size_t)(N + 1) * sizeof(int));
    uint*  binned   = (uint*)alloc((size_t)E * sizeof(uint));          // 3.2 MB
    uint*  csr      = (uint*)alloc((size_t)E * sizeof(uint));          // 3.2 MB
    int*   histm    = (int*)alloc((size_t)nchunk * nhi * sizeof(int)); // 154 KB
    int*   colsum   = (int*)alloc((size_t)nhi * sizeof(int));
    int*   bin_base = (int*)alloc((size_t)(nhi + 1) * sizeof(int));

    const int gblocks = (N + GROWS - 1) / GROWS;  // 782

    convW_kernel<<<64, 256, 0, stream>>>(W, Wtg);
    gemm_mfma_kernel<<<gblocks, 512, 0, stream>>>(h, Wtg, attn, zb, ssrc, sdst, N);
    binA_kernel<<<nchunk, 256, 0, stream>>>(dst, histm, nhi, E);
    binB1_kernel<<<nhi, 64, 0, stream>>>(histm, colsum, nhi, nchunk);
    binB2_kernel<<<1, 256, 0, stream>>>(colsum, bin_base, nhi, E);
    binC_kernel<<<nchunk, 256, 0, stream>>>(src, dst, et, histm, bin_base, binned, nhi, E);
    binD_kernel<<<nhi, 256, 0, stream>>>(binned, bin_base, offsets, csr, N, E);
    aggregate_kernel<<<(N + 3) / 4, 256, 0, stream>>>((const uint*)zb, ssrc, sdst,
                                                      offsets, csr, rel, out, N, R);
}